// Round 3
// baseline (33.994 us; speedup 1.0000x reference)
//
#include <hip/hip_runtime.h>

#define TPB 512
#define NDIM 8

typedef float fvec4 __attribute__((ext_vector_type(4)));

__global__ __launch_bounds__(TPB, 8) void vegas_map_kernel(
    const float* __restrict__ u,      // [n, 8]
    const float* __restrict__ grid,   // [8, gcols]
    float* __restrict__ x_out,        // [n, 8]
    float* __restrict__ lj_out,       // [n]
    int n, int gcols)
{
    extern __shared__ float lds_grid[];   // 8 * gcols floats (32 KB for gcols=1001)
    const int ninc = gcols - 1;
    const int gtot4 = (NDIM * gcols) >> 2;   // 8*gcols always divisible by 4

    // Stage grid table into LDS with 16B loads (coalesced, conflict-free).
    const fvec4* __restrict__ g4 = (const fvec4*)grid;
    fvec4* lds4 = (fvec4*)lds_grid;
    for (int t = threadIdx.x; t < gtot4; t += TPB)
        lds4[t] = g4[t];
    __syncthreads();

    const float fninc = (float)ninc;
    const fvec4* __restrict__ u4 = (const fvec4*)u;
    fvec4* __restrict__ x4 = (fvec4*)x_out;

    const int stride = gridDim.x * TPB;

    for (int p = blockIdx.x * TPB + threadIdx.x; p < n; p += 2 * stride) {
        const int q = p + stride;
        const bool hq = (q < n);

        // Issue all u loads up front (max memory-level parallelism).
        fvec4 a0 = __builtin_nontemporal_load(u4 + 2 * p);
        fvec4 b0 = __builtin_nontemporal_load(u4 + 2 * p + 1);
        fvec4 a1 = a0, b1 = b0;
        if (hq) {
            a1 = __builtin_nontemporal_load(u4 + 2 * q);
            b1 = __builtin_nontemporal_load(u4 + 2 * q + 1);
        }

        #pragma unroll
        for (int pt = 0; pt < 2; ++pt) {
            if (pt == 1 && !hq) break;
            const int idx = (pt == 0) ? p : q;
            float uv[NDIM];
            if (pt == 0) {
                uv[0]=a0.x; uv[1]=a0.y; uv[2]=a0.z; uv[3]=a0.w;
                uv[4]=b0.x; uv[5]=b0.y; uv[6]=b0.z; uv[7]=b0.w;
            } else {
                uv[0]=a1.x; uv[1]=a1.y; uv[2]=a1.z; uv[3]=a1.w;
                uv[4]=b1.x; uv[5]=b1.y; uv[6]=b1.z; uv[7]=b1.w;
            }

            float xv[NDIM];
            float prod = 1.0f;
            #pragma unroll
            for (int d = 0; d < NDIM; ++d) {
                float un = uv[d] * fninc;
                int   iu = (int)un;            // trunc == floor (un >= 0)
                float du = un - (float)iu;
                bool  in = iu < ninc;
                int   iuc = in ? iu : (ninc - 1);
                const float* row = lds_grid + d * gcols;
                float g0 = row[iuc];
                float g1 = row[iuc + 1];       // adjacent -> ds_read2-friendly
                float h  = g1 - g0;            // == inc[d][iuc] bit-exactly
                xv[d] = in ? (g0 + h * du) : row[ninc];
                prod *= h * fninc;             // fac; at upper edge h == inc_last
            }

            fvec4 oa = {xv[0], xv[1], xv[2], xv[3]};
            fvec4 ob = {xv[4], xv[5], xv[6], xv[7]};
            __builtin_nontemporal_store(oa, x4 + 2 * idx);
            __builtin_nontemporal_store(ob, x4 + 2 * idx + 1);
            __builtin_nontemporal_store(logf(prod), lj_out + idx);  // sum(log) == log(prod)
        }
    }
}

extern "C" void kernel_launch(void* const* d_in, const int* in_sizes, int n_in,
                              void* d_out, int out_size, void* d_ws, size_t ws_size,
                              hipStream_t stream) {
    const float* u    = (const float*)d_in[0];   // [N, 8]
    const float* grid = (const float*)d_in[1];   // [8, ninc+1]
    // d_in[2] = inc (recomputed as adjacent grid diffs), d_in[3] = ninc (derived)
    const int n     = in_sizes[0] / NDIM;
    const int gcols = in_sizes[1] / NDIM;        // ninc + 1

    float* x_out  = (float*)d_out;
    float* lj_out = (float*)d_out + (size_t)n * NDIM;

    int blocks = (n + TPB - 1) / TPB;
    if (blocks > 1024) blocks = 1024;            // 4 blocks/CU x 256 CUs, persistent
    size_t lds_bytes = (size_t)NDIM * gcols * sizeof(float);

    vegas_map_kernel<<<blocks, TPB, lds_bytes, stream>>>(u, grid, x_out, lj_out, n, gcols);
}